// Round 1
// baseline (748.521 us; speedup 1.0000x reference)
//
#include <hip/hip_runtime.h>
#include <math.h>

#define B_   32
#define N_   1024
#define C_   4096
#define HC_  2048
#define D_   64
#define NT_  32768           // B*N tokens
#define KS_  8               // K splits for the P-GEMM
#define KC_  (HC_ / KS_)     // 256 columns per split
#define BKC_ 32              // K-chunk per staging step

__device__ __forceinline__ float4 ld4(const float* p) {
    return *reinterpret_cast<const float4*>(p);
}

// ---------------------------------------------------------------------------
// K1: per-row LN stats + deterministic per-group accumulation of normalized
// upper half.  grid 4096 = 32 batches * 128 groups of 8 rows, block 256.
// ---------------------------------------------------------------------------
__global__ __launch_bounds__(256) void k1_stats(
        const float* __restrict__ x, const float* __restrict__ lnw,
        const float* __restrict__ lnb, float* __restrict__ muv,
        float* __restrict__ rsv, float* __restrict__ part) {
    __shared__ float up[HC_];     // stash of a row's upper half
    __shared__ float gacc[HC_];   // group accumulator of xn-upper
    __shared__ float red[8];
    __shared__ float mrs[2];

    const int t = threadIdx.x;
    const int bid = blockIdx.x;
    const int b = bid >> 7;       // batch
    const int g = bid & 127;      // row group (8 rows)

    for (int j = t; j < HC_; j += 256) gacc[j] = 0.f;

    // per-thread ln_w / ln_b upper-half values (strided t, t+256, ...)
    float wreg[8], breg[8];
#pragma unroll
    for (int p = 0; p < 8; ++p) {
        wreg[p] = lnw[HC_ + t + p * 256];
        breg[p] = lnb[HC_ + t + p * 256];
    }
    __syncthreads();

    for (int i = 0; i < 8; ++i) {
        const int n = g * 8 + i;
        const float* row = x + (size_t)(b * N_ + n) * C_;
        float s = 0.f, q = 0.f;
#pragma unroll
        for (int p = 0; p < 4; ++p) {
            float4 v = ld4(row + p * 1024 + t * 4);
            s += v.x + v.y + v.z + v.w;
            q += v.x * v.x + v.y * v.y + v.z * v.z + v.w * v.w;
            if (p >= 2)
                *reinterpret_cast<float4*>(&up[(p - 2) * 1024 + t * 4]) = v;
        }
        // block reduction of s,q
#pragma unroll
        for (int o = 32; o > 0; o >>= 1) {
            s += __shfl_down(s, o);
            q += __shfl_down(q, o);
        }
        const int wid = t >> 6, ln = t & 63;
        if (ln == 0) { red[wid * 2] = s; red[wid * 2 + 1] = q; }
        __syncthreads();
        if (t == 0) {
            float S = red[0] + red[2] + red[4] + red[6];
            float Q = red[1] + red[3] + red[5] + red[7];
            float mu = S * (1.f / C_);
            float var = Q * (1.f / C_) - mu * mu;
            float rs = rsqrtf(var + 1e-5f);
            mrs[0] = mu; mrs[1] = rs;
            muv[b * N_ + n] = mu;
            rsv[b * N_ + n] = rs;
        }
        __syncthreads();
        const float mu = mrs[0], rs = mrs[1];
#pragma unroll
        for (int p = 0; p < 8; ++p) {
            const int j = t + p * 256;
            gacc[j] += (up[j] - mu) * rs * wreg[p] + breg[p];
        }
        __syncthreads();   // protects up[] and red[] for next row
    }
#pragma unroll
    for (int p = 0; p < 8; ++p) {
        const int j = t + p * 256;
        part[(size_t)bid * HC_ + j] = gacc[j];
    }
}

// ---------------------------------------------------------------------------
// K1b: reduce 128 group partials -> G[b][j].  grid 256, block 256.
// ---------------------------------------------------------------------------
__global__ __launch_bounds__(256) void k1b_reduce(
        const float* __restrict__ part, float* __restrict__ G) {
    const int t = threadIdx.x;
    const int b = blockIdx.x >> 3;
    const int j = ((blockIdx.x & 7) << 8) + t;
    float a = 0.f;
    for (int g = 0; g < 128; ++g)
        a += part[(size_t)(b * 128 + g) * HC_ + j];
    G[b * HC_ + j] = a;
}

// ---------------------------------------------------------------------------
// K2: gterm[b,d] (b<32) and W1s/Bs (b==32).  grid 33, block 64.
// ---------------------------------------------------------------------------
__global__ __launch_bounds__(64) void k2_small(
        const float* __restrict__ G, const float* __restrict__ w1,
        const float* __restrict__ lnw, const float* __restrict__ lnb,
        float* __restrict__ gterm, float* __restrict__ W1s,
        float* __restrict__ Bs) {
    const int d = threadIdx.x;
    const int b = blockIdx.x;
    if (b < B_) {
        float a = 0.f;
        for (int j = 0; j < HC_; ++j)
            a = fmaf(G[b * HC_ + j], w1[(size_t)(HC_ + j) * D_ + d], a);
        gterm[b * D_ + d] = a * (1.f / N_);
    } else {
        float a = 0.f, c2 = 0.f;
        for (int c = 0; c < HC_; ++c) {
            float wv = w1[(size_t)c * D_ + d];
            a = fmaf(lnw[c], wv, a);
            c2 = fmaf(lnb[c], wv, c2);
        }
        W1s[d] = a;
        Bs[d] = c2;
    }
}

// ---------------------------------------------------------------------------
// K3: P-GEMM  P[t,d] = sum_c (x[t,c]*lnw[c]) * w1[c,d],  c in this block's
// K-split.  lane = row (64 rows/wave, 256 rows/block), w1 via wave-uniform
// loads (expect s_load), x per-lane regs from XOR-swizzled LDS.
// grid = KS_*128 = 1024, block 256.
// ---------------------------------------------------------------------------
__global__ __launch_bounds__(256, 4) void k3_gemm(
        const float* __restrict__ x, const float* __restrict__ lnw,
        const float* __restrict__ w1, float* __restrict__ Pp) {
    __shared__ float xs[256 * BKC_];   // 32 KiB, XOR-swizzled rows of 128B

    const int t = threadIdx.x;
    const int mt = blockIdx.x & 127;   // M tile (256 rows)
    const int ks = blockIdx.x >> 7;    // K split
    const int T0 = mt * 256;
    const int kbase = ks * KC_;
    const int w = t >> 6, lane = t & 63;
    const int myr = w * 64 + lane;

    float acc[D_];
#pragma unroll
    for (int d = 0; d < D_; ++d) acc[d] = 0.f;

    for (int kc = 0; kc < KC_; kc += BKC_) {
        const int k0 = kbase + kc;
        // --- stage 256 rows x 32 cols, folding ln_w ---
#pragma unroll
        for (int p = 0; p < 8; ++p) {
            const int r = p * 32 + (t >> 3);
            const int slot = t & 7;                    // 16B slot in row
            const float* src = x + (size_t)(T0 + r) * C_ + k0 + slot * 4;
            float4 v = ld4(src);
            float4 wv = ld4(lnw + k0 + slot * 4);
            v.x *= wv.x; v.y *= wv.y; v.z *= wv.z; v.w *= wv.w;
            const int byteoff = r * 128 + ((slot * 16) ^ ((r & 7) << 4));
            *reinterpret_cast<float4*>(reinterpret_cast<char*>(xs) + byteoff) = v;
        }
        __syncthreads();
        // --- my row's chunk to regs (conflict-free b128) ---
        float xr[BKC_];
#pragma unroll
        for (int c4 = 0; c4 < 8; ++c4) {
            const int byteoff = myr * 128 + ((c4 * 16) ^ ((myr & 7) << 4));
            float4 v = *reinterpret_cast<const float4*>(
                reinterpret_cast<const char*>(xs) + byteoff);
            xr[c4 * 4 + 0] = v.x; xr[c4 * 4 + 1] = v.y;
            xr[c4 * 4 + 2] = v.z; xr[c4 * 4 + 3] = v.w;
        }
        // --- FMAs: w1 address wave-uniform -> scalar loads expected ---
#pragma unroll
        for (int c = 0; c < BKC_; ++c) {
            const float* wr = w1 + (size_t)(k0 + c) * D_;
            const float xc = xr[c];
#pragma unroll
            for (int d = 0; d < D_; ++d)
                acc[d] = fmaf(xc, wr[d], acc[d]);
        }
        __syncthreads();
    }
    float* dst = Pp + ((size_t)ks * NT_ + T0 + myr) * D_;
#pragma unroll
    for (int d4 = 0; d4 < 16; ++d4)
        *reinterpret_cast<float4*>(dst + d4 * 4) =
            make_float4(acc[d4 * 4], acc[d4 * 4 + 1],
                        acc[d4 * 4 + 2], acc[d4 * 4 + 3]);
}

// ---------------------------------------------------------------------------
// K4: per-token decision.  wave per token (lane = d).  grid 8192, block 256.
// ---------------------------------------------------------------------------
__global__ __launch_bounds__(256) void k4_decide(
        const float* __restrict__ Pp, const float* __restrict__ muv,
        const float* __restrict__ rsv, const float* __restrict__ gterm,
        const float* __restrict__ W1s, const float* __restrict__ Bs,
        const float* __restrict__ b1, const float* __restrict__ w2,
        const float* __restrict__ b2, const float* __restrict__ gum,
        float* __restrict__ keep) {
    const int t = threadIdx.x;
    const int lane = t & 63, wv = t >> 6;
    const int token = blockIdx.x * 4 + wv;
    const int b = token >> 10;

    float p = 0.f;
#pragma unroll
    for (int s = 0; s < KS_; ++s)
        p += Pp[((size_t)s * NT_ + token) * D_ + lane];

    const float mu = muv[token], rs = rsv[token];
    float h = rs * (p - mu * W1s[lane]) + Bs[lane] + gterm[b * D_ + lane]
              + b1[lane];
    h = 0.5f * h * (1.f + erff(h * 0.70710678118654752f));   // exact gelu
    float l0 = h * w2[lane * 2];
    float l1 = h * w2[lane * 2 + 1];
#pragma unroll
    for (int o = 32; o > 0; o >>= 1) {
        l0 += __shfl_down(l0, o);
        l1 += __shfl_down(l1, o);
    }
    if (lane == 0) {
        const float z0 = l0 + b2[0] + gum[token * 2];
        const float z1 = l1 + b2[1] + gum[token * 2 + 1];
        keep[token] = (z0 >= z1) ? 1.f : 0.f;   // argmax ties -> index 0
    }
}

// ---------------------------------------------------------------------------
// K5: out = x * keep[token].  grid 32768 (one row/block), block 256.
// ---------------------------------------------------------------------------
__global__ __launch_bounds__(256) void k5_mask(
        const float* __restrict__ x, const float* __restrict__ keep,
        float* __restrict__ out) {
    const int token = blockIdx.x;
    const float kv = keep[token];
    const float4* src = reinterpret_cast<const float4*>(x + (size_t)token * C_);
    float4* dst = reinterpret_cast<float4*>(out + (size_t)token * C_);
    const int t = threadIdx.x;
#pragma unroll
    for (int p = 0; p < 4; ++p) {
        float4 v = src[p * 256 + t];
        v.x *= kv; v.y *= kv; v.z *= kv; v.w *= kv;
        dst[p * 256 + t] = v;
    }
}

// ---------------------------------------------------------------------------
extern "C" void kernel_launch(void* const* d_in, const int* in_sizes, int n_in,
                              void* d_out, int out_size, void* d_ws,
                              size_t ws_size, hipStream_t stream) {
    const float* x   = (const float*)d_in[0];
    const float* gum = (const float*)d_in[1];
    const float* lnw = (const float*)d_in[2];
    const float* lnb = (const float*)d_in[3];
    const float* w1  = (const float*)d_in[4];
    const float* b1  = (const float*)d_in[5];
    const float* w2  = (const float*)d_in[6];
    const float* b2  = (const float*)d_in[7];
    float* out = (float*)d_out;

    float* wsf   = (float*)d_ws;
    float* Pp    = wsf;                                   // 8*32768*64
    float* muv   = Pp + (size_t)KS_ * NT_ * D_;           // 32768
    float* rsv   = muv + NT_;                             // 32768
    float* part  = rsv + NT_;                             // 4096*2048
    float* G     = part + (size_t)4096 * HC_;             // 32*2048
    float* gterm = G + B_ * HC_;                          // 32*64
    float* W1s   = gterm + B_ * D_;                       // 64
    float* Bs    = W1s + D_;                              // 64
    float* keep  = Bs + D_;                               // 32768

    k1_stats<<<4096, 256, 0, stream>>>(x, lnw, lnb, muv, rsv, part);
    k1b_reduce<<<256, 256, 0, stream>>>(part, G);
    k2_small<<<33, 64, 0, stream>>>(G, w1, lnw, lnb, gterm, W1s, Bs);
    k3_gemm<<<KS_ * 128, 256, 0, stream>>>(x, lnw, w1, Pp);
    k4_decide<<<NT_ / 4, 256, 0, stream>>>(Pp, muv, rsv, gterm, W1s, Bs,
                                           b1, w2, b2, gum, keep);
    k5_mask<<<NT_, 256, 0, stream>>>(x, keep, out);
}